// Round 7
// baseline (96.024 us; speedup 1.0000x reference)
//
#include <hip/hip_runtime.h>
#include <hip/hip_bf16.h>

#define T_BINS 64
#define EPSF 1e-9f
#define ROWS_PER_WAVE 32
#define ROWS_PER_BLOCK 128          // 4 waves * 32 rows
#define NBLOCKS 2048                // fixed grid; rows guarded by N
#define NGROUPS 64                  // level-1 ticket lines
#define GROUP_SIZE (NBLOCKS / NGROUPS)   // 32 (power of 2 -> any-init residue)

// softplus(x) = ln2 * log2(1 + e^x) — exact for |x| < 80 (preds ~ N(0,1)).
// ln2 pre-folded into weights. Event-at-d: softplus(-x) = softplus(x) - x.

__global__ __launch_bounds__(256) void nll_hazard_fused(
    const float* __restrict__ preds,          // [N, 64]
    const float* __restrict__ weight,         // [64]
    const float* __restrict__ sample_weight,  // [N]
    const int*   __restrict__ durations,      // [N]
    const int*   __restrict__ events,         // [N]
    float* __restrict__ partial_loss,         // [NBLOCKS]
    float* __restrict__ partial_sw,           // [NBLOCKS]
    unsigned int* __restrict__ tickets,       // [NGROUPS*16] spread, any init
    unsigned int* __restrict__ ticket2,       // [1], any init
    float* __restrict__ out,
    int N)
{
    const int lane      = threadIdx.x & 63;
    const int waveInBlk = threadIdx.x >> 6;
    const int q  = lane & 15;       // column-quad within a row
    const int g  = lane >> 4;       // which of 4 rows this lane serves per iter
    const int c0 = q << 2;          // first column this lane covers

    const int R = blockIdx.x * ROWS_PER_BLOCK + waveInBlk * ROWS_PER_WAVE;

    const float LN2 = 0.6931471805599453f;
    const float4 w4 = *reinterpret_cast<const float4*>(weight + c0);
    const float wv[4] = {w4.x, w4.y, w4.z, w4.w};
    const float wl[4] = {w4.x * LN2, w4.y * LN2, w4.z * LN2, w4.w * LN2};
    const float4* __restrict__ preds4 = reinterpret_cast<const float4*>(preds);

    // ---- ONE coalesced scalar batch for the wave's 32 rows.
    const int sr = R + (lane & 31);
    int   de  = -1;                 // d | e<<8 ; -1 = invalid row
    float swv = 0.0f;
    if (sr < N) {
        const int d = min(max(durations[sr], 0), T_BINS - 1);
        de  = d | (events[sr] != 0 ? 256 : 0);
        swv = sample_weight[sr];
    }
    float acc_sw = (lane < 32) ? swv : 0.0f;

    int de_i[8];
    #pragma unroll
    for (int i = 0; i < 8; ++i) de_i[i] = __shfl(de, 4 * i + g, 64);

    // ---- All 8 predicated float4 loads in flight.
    float4 x[8];
    #pragma unroll
    for (int i = 0; i < 8; ++i) {
        const int d = de_i[i] & 255;
        x[i] = make_float4(0.f, 0.f, 0.f, 0.f);
        if (de_i[i] >= 0 && c0 <= d) {
            x[i] = preds4[(size_t)(R + 4 * i) * 16 + lane];
        }
    }

    // ---- Compute.
    float acc = 0.0f;
    #pragma unroll
    for (int i = 0; i < 8; ++i) {
        const int  d = de_i[i] & 255;
        const bool valid = de_i[i] >= 0;
        const bool e = (de_i[i] & 256) != 0;
        const float sw_i = __shfl(swv, 4 * i + g, 64);
        const float xv[4] = {x[i].x, x[i].y, x[i].z, x[i].w};
        float rowAcc = 0.0f;
        #pragma unroll
        for (int j = 0; j < 4; ++j) {
            const int c = c0 + j;
            const float lg = __log2f(1.0f + __expf(xv[j]));  // masked lanes: x=0 -> lg=1, *0
            const float ws = (valid && c <= d) ? wl[j] : 0.0f;
            rowAcc = fmaf(lg, ws, rowAcc);
            if (valid && e && c == d) rowAcc = fmaf(-wv[j], xv[j], rowAcc);
        }
        acc = fmaf(rowAcc, sw_i, acc);
    }

    // ---- Wave butterfly + block LDS reduce.
    #pragma unroll
    for (int off = 32; off >= 1; off >>= 1) {
        acc    += __shfl_xor(acc,    off, 64);
        acc_sw += __shfl_xor(acc_sw, off, 64);
    }

    __shared__ float s_loss[4];
    __shared__ float s_sw[4];
    __shared__ int   s_last;
    if (lane == 0) {
        s_loss[waveInBlk] = acc;
        s_sw[waveInBlk]   = acc_sw;
    }
    __syncthreads();

    // ---- Partial store + HIERARCHICAL spread ticket (no same-line storm:
    // level-1 = 64 separate lines x 32 increments, level-2 = 1 line x 64).
    if (threadIdx.x == 0) {
        float bl = 0.f, bs = 0.f;
        #pragma unroll
        for (int w = 0; w < 4; ++w) { bl += s_loss[w]; bs += s_sw[w]; }
        __hip_atomic_store(&partial_loss[blockIdx.x], bl,
                           __ATOMIC_RELAXED, __HIP_MEMORY_SCOPE_AGENT);
        __hip_atomic_store(&partial_sw[blockIdx.x], bs,
                           __ATOMIC_RELAXED, __HIP_MEMORY_SCOPE_AGENT);
        __threadfence();  // release partials before ticketing

        const int grp = blockIdx.x & (NGROUPS - 1);
        const unsigned int o1 = __hip_atomic_fetch_add(
            &tickets[grp << 4], 1u, __ATOMIC_ACQ_REL, __HIP_MEMORY_SCOPE_AGENT);
        int lastAll = 0;
        if ((o1 & (GROUP_SIZE - 1)) == (GROUP_SIZE - 1)) {   // last in group
            const unsigned int o2 = __hip_atomic_fetch_add(
                ticket2, 1u, __ATOMIC_ACQ_REL, __HIP_MEMORY_SCOPE_AGENT);
            lastAll = ((o2 & (NGROUPS - 1)) == (NGROUPS - 1));
        }
        s_last = lastAll;
    }
    __syncthreads();

    // ---- Winner block reduces all 2048 partial pairs and writes out.
    if (s_last) {
        __threadfence();  // acquire (all threads; chain via acq_rel RMWs)
        const int t = threadIdx.x;
        float l = 0.f, s = 0.f;
        #pragma unroll
        for (int k = 0; k < 8; ++k) {
            l += __hip_atomic_load(&partial_loss[t + (k << 8)],
                                   __ATOMIC_RELAXED, __HIP_MEMORY_SCOPE_AGENT);
            s += __hip_atomic_load(&partial_sw[t + (k << 8)],
                                   __ATOMIC_RELAXED, __HIP_MEMORY_SCOPE_AGENT);
        }
        #pragma unroll
        for (int off = 32; off >= 1; off >>= 1) {
            l += __shfl_xor(l, off, 64);
            s += __shfl_xor(s, off, 64);
        }
        __shared__ float rl[4];
        __shared__ float rs[4];
        if (lane == 0) { rl[waveInBlk] = l; rs[waveInBlk] = s; }
        __syncthreads();
        if (t == 0) {
            float L = 0.f, S = 0.f;
            #pragma unroll
            for (int w = 0; w < 4; ++w) { L += rl[w]; S += rs[w]; }
            out[0] = L / fmaxf(S, EPSF);
        }
    }
}

extern "C" void kernel_launch(void* const* d_in, const int* in_sizes, int n_in,
                              void* d_out, int out_size, void* d_ws, size_t ws_size,
                              hipStream_t stream) {
    const float* preds         = (const float*)d_in[0];
    const float* weight        = (const float*)d_in[1];
    const float* sample_weight = (const float*)d_in[2];
    const int*   durations     = (const int*)d_in[3];
    const int*   events        = (const int*)d_in[4];
    float* out = (float*)d_out;

    const int N = in_sizes[2];  // sample_weight has N elements (262144 here)

    float* partial_loss = (float*)d_ws;                       // [NBLOCKS]
    float* partial_sw   = partial_loss + NBLOCKS;             // [NBLOCKS]
    unsigned int* tickets = (unsigned int*)(partial_sw + NBLOCKS);  // [64*16] spread
    unsigned int* ticket2 = tickets + NGROUPS * 16;           // [1]

    nll_hazard_fused<<<NBLOCKS, 256, 0, stream>>>(
        preds, weight, sample_weight, durations, events,
        partial_loss, partial_sw, tickets, ticket2, out, N);
}

// Round 8
// 20.332 us; speedup vs baseline: 4.7229x; 4.7229x over previous
//
#include <hip/hip_runtime.h>
#include <hip/hip_bf16.h>

#define T_BINS 64
#define EPSF 1e-9f
#define ROWS_PER_WAVE 32
#define ROWS_PER_BLOCK 128   // 4 waves * 32 rows

// softplus(x) = ln2 * log2(1 + e^x) — exact for |x| < 80 (preds ~ N(0,1)).
// ln2 pre-folded into weights. Event-at-d: softplus(-x) = softplus(x) - x.
// Columns with c > d contribute via weight 0, so loading real (unused) x
// values unconditionally is numerically safe.

__global__ __launch_bounds__(256) void nll_hazard_main(
    const float* __restrict__ preds,          // [N, 64]
    const float* __restrict__ weight,         // [64]
    const float* __restrict__ sample_weight,  // [N]
    const int*   __restrict__ durations,      // [N]
    const int*   __restrict__ events,         // [N]
    float* __restrict__ partial_loss,         // [nblocks]
    float* __restrict__ partial_sw,           // [nblocks]
    int N)
{
    const int lane      = threadIdx.x & 63;
    const int waveInBlk = threadIdx.x >> 6;
    const int q  = lane & 15;       // column-quad within a row
    const int g  = lane >> 4;       // which of 4 rows this lane serves per iter
    const int c0 = q << 2;          // first column this lane covers

    // This wave owns rows [R, R+32).
    const int R = blockIdx.x * ROWS_PER_BLOCK + waveInBlk * ROWS_PER_WAVE;

    const float4* __restrict__ preds4 = reinterpret_cast<const float4*>(preds);

    // ---- HOP-0: loads with NO data dependency, issued first. ----
    // x[0..3]: rows R..R+15, FULL rows (unconditional). This overlaps the
    // scalar-load latency (hop 1) with half the preds traffic.
    float4 x[8];
    #pragma unroll
    for (int i = 0; i < 4; ++i) {
        x[i] = preds4[(size_t)(R + 4 * i) * 16 + lane];
    }

    // Coalesced scalar batch for the wave's 32 rows (lanes 0..31 distinct).
    const int sr = R + (lane & 31);
    int   de  = -1;                 // d | e<<8 ; -1 = invalid row
    float swv = 0.0f;
    if (sr < N) {
        const int d = min(max(durations[sr], 0), T_BINS - 1);
        de  = d | (events[sr] != 0 ? 256 : 0);
        swv = sample_weight[sr];
    }
    float acc_sw = (lane < 32) ? swv : 0.0f;

    const float LN2 = 0.6931471805599453f;
    const float4 w4 = *reinterpret_cast<const float4*>(weight + c0);
    const float wv[4] = {w4.x, w4.y, w4.z, w4.w};
    const float wl[4] = {w4.x * LN2, w4.y * LN2, w4.z * LN2, w4.w * LN2};

    int de_i[8];
    #pragma unroll
    for (int i = 0; i < 8; ++i) de_i[i] = __shfl(de, 4 * i + g, 64);

    // ---- HOP-1-dependent: rows R+16..R+31 predicated on d (fetch saving).
    #pragma unroll
    for (int i = 4; i < 8; ++i) {
        const int d = de_i[i] & 255;
        x[i] = make_float4(0.f, 0.f, 0.f, 0.f);
        if (de_i[i] >= 0 && c0 <= d) {
            x[i] = preds4[(size_t)(R + 4 * i) * 16 + lane];
        }
    }

    // ---- Compute.
    float acc = 0.0f;
    #pragma unroll
    for (int i = 0; i < 8; ++i) {
        const int  d = de_i[i] & 255;
        const bool valid = de_i[i] >= 0;
        const bool e = (de_i[i] & 256) != 0;
        const float sw_i = __shfl(swv, 4 * i + g, 64);
        const float xv[4] = {x[i].x, x[i].y, x[i].z, x[i].w};
        float rowAcc = 0.0f;
        #pragma unroll
        for (int j = 0; j < 4; ++j) {
            const int c = c0 + j;
            const float lg = __log2f(1.0f + __expf(xv[j]));  // masked: *0 below
            const float ws = (valid && c <= d) ? wl[j] : 0.0f;
            rowAcc = fmaf(lg, ws, rowAcc);
            if (valid && e && c == d) rowAcc = fmaf(-wv[j], xv[j], rowAcc);
        }
        acc = fmaf(rowAcc, sw_i, acc);
    }

    // ---- Wave butterfly reduction.
    #pragma unroll
    for (int off = 32; off >= 1; off >>= 1) {
        acc    += __shfl_xor(acc,    off, 64);
        acc_sw += __shfl_xor(acc_sw, off, 64);
    }

    // ---- Block LDS reduce -> one plain store per block (NO atomics, NO
    // fences: device-scope release ≈ 50 ns/block serialized, Rounds 5/7).
    __shared__ float s_loss[4];
    __shared__ float s_sw[4];
    if (lane == 0) {
        s_loss[waveInBlk] = acc;
        s_sw[waveInBlk]   = acc_sw;
    }
    __syncthreads();
    if (threadIdx.x == 0) {
        float bl = 0.f, bs = 0.f;
        #pragma unroll
        for (int w = 0; w < 4; ++w) { bl += s_loss[w]; bs += s_sw[w]; }
        partial_loss[blockIdx.x] = bl;
        partial_sw[blockIdx.x]   = bs;
    }
}

// Single block (512 threads) sums nblocks<=2048 partial pairs via float4.
// (Kept byte-identical to Round 6 so the total delta isolates main.)
__global__ __launch_bounds__(512) void nll_hazard_reduce(
    const float* __restrict__ partial_loss,
    const float* __restrict__ partial_sw,
    float* __restrict__ out,
    int nblocks)
{
    const int t    = threadIdx.x;
    const int lane = t & 63;
    const int wid  = t >> 6;

    float l = 0.f, s = 0.f;
    const int nvec = nblocks >> 2;   // nblocks multiple of 4 (grid sizing)
    if (t < nvec) {
        const float4 l4 = reinterpret_cast<const float4*>(partial_loss)[t];
        const float4 s4 = reinterpret_cast<const float4*>(partial_sw)[t];
        l = (l4.x + l4.y) + (l4.z + l4.w);
        s = (s4.x + s4.y) + (s4.z + s4.w);
    }

    #pragma unroll
    for (int off = 32; off >= 1; off >>= 1) {
        l += __shfl_xor(l, off, 64);
        s += __shfl_xor(s, off, 64);
    }

    __shared__ float sl[8];
    __shared__ float ss[8];
    if (lane == 0) { sl[wid] = l; ss[wid] = s; }
    __syncthreads();
    if (t == 0) {
        float L = 0.f, S = 0.f;
        #pragma unroll
        for (int w = 0; w < 8; ++w) { L += sl[w]; S += ss[w]; }
        out[0] = L / fmaxf(S, EPSF);
    }
}

extern "C" void kernel_launch(void* const* d_in, const int* in_sizes, int n_in,
                              void* d_out, int out_size, void* d_ws, size_t ws_size,
                              hipStream_t stream) {
    const float* preds         = (const float*)d_in[0];
    const float* weight        = (const float*)d_in[1];
    const float* sample_weight = (const float*)d_in[2];
    const int*   durations     = (const int*)d_in[3];
    const int*   events        = (const int*)d_in[4];
    float* out = (float*)d_out;

    const int N = in_sizes[2];  // sample_weight has N elements

    const int nblocks = (N + ROWS_PER_BLOCK - 1) / ROWS_PER_BLOCK;  // 2048

    float* partial_loss = (float*)d_ws;             // [nblocks]
    float* partial_sw   = partial_loss + nblocks;   // [nblocks]

    nll_hazard_main<<<nblocks, 256, 0, stream>>>(
        preds, weight, sample_weight, durations, events,
        partial_loss, partial_sw, N);

    nll_hazard_reduce<<<1, 512, 0, stream>>>(partial_loss, partial_sw, out, nblocks);
}

// Round 10
// 18.618 us; speedup vs baseline: 5.1576x; 1.0921x over previous
//
#include <hip/hip_runtime.h>
#include <hip/hip_bf16.h>

#define T_BINS 64
#define EPSF 1e-9f
#define ROWS_PER_WAVE 32
#define ROWS_PER_BLOCK 128   // 4 waves * 32 rows

// Per-row loss:  sw * [ sum_{j<=d} w_j*softplus(x_j) ]  -  sw*e*w_d*x_d
// (uses softplus(-x) = softplus(x) - x for the event bin.)
// softplus(x) = ln2*log2(1 + e^x); ln2 folded into weights.
// Masking: x' = (c<=d) ? x : -1e9  =>  e^x' = 0, log2(1) = 0 exactly.

__global__ __launch_bounds__(256) void nll_hazard_main(
    const float* __restrict__ preds,          // [N, 64]
    const float* __restrict__ weight,         // [64]
    const float* __restrict__ sample_weight,  // [N]
    const int*   __restrict__ durations,      // [N]
    const int*   __restrict__ events,         // [N]
    float* __restrict__ partial_loss,         // [nblocks]
    float* __restrict__ partial_sw,           // [nblocks]
    int N)
{
    const int lane      = threadIdx.x & 63;
    const int waveInBlk = threadIdx.x >> 6;
    const int q  = lane & 15;       // column-quad within a row
    const int g  = lane >> 4;       // which of 4 rows this lane serves per iter
    const int c0 = q << 2;          // first column this lane covers

    // This wave owns rows [R, R+32).
    const int R = blockIdx.x * ROWS_PER_BLOCK + waveInBlk * ROWS_PER_WAVE;

    const float4* __restrict__ preds4 = reinterpret_cast<const float4*>(preds);

    // ---- Coalesced scalar batch: lane s (=lane&31) owns row R+s. ----
    const int sr = R + (lane & 31);
    int   dv  = -1;      // clamped duration; -1 = invalid row (masks everything)
    float swv = 0.0f;    // sample weight
    float ecv = 0.0f;    // event coefficient: e ? sw * weight[d] : 0
    if (sr < N) {
        const int d = min(max(durations[sr], 0), T_BINS - 1);
        dv  = d;
        swv = sample_weight[sr];
        if (events[sr] != 0) ecv = swv * weight[d];   // 64-entry gather (L1-hot)
    }
    float acc_sw = (lane < 32) ? swv : 0.0f;

    const float LN2 = 0.6931471805599453f;
    const float4 w4 = *reinterpret_cast<const float4*>(weight + c0);
    const float wl[4] = {w4.x * LN2, w4.y * LN2, w4.z * LN2, w4.w * LN2};

    // Redistribute row scalars to the 16-lane groups that compute them.
    int d_i[8]; float sw_i[8]; float ec_i[8];
    #pragma unroll
    for (int i = 0; i < 8; ++i) {
        const int src = 4 * i + g;
        d_i[i]  = __shfl(dv,  src, 64);
        sw_i[i] = __shfl(swv, src, 64);
        ec_i[i] = __shfl(ecv, src, 64);
    }

    // ---- All 8 predicated float4 loads in flight (prefix-only fetch). ----
    float4 x[8];
    #pragma unroll
    for (int i = 0; i < 8; ++i) {
        x[i] = make_float4(0.f, 0.f, 0.f, 0.f);
        if (c0 <= d_i[i]) {                 // d_i = -1 -> never loads
            x[i] = preds4[(size_t)(R + 4 * i) * 16 + lane];
        }
    }

    // ---- Compute: ~7 VALU/element + ~9/row event fixup. ----
    float acc = 0.0f;
    #pragma unroll
    for (int i = 0; i < 8; ++i) {
        const int d = d_i[i];
        const float xv[4] = {x[i].x, x[i].y, x[i].z, x[i].w};
        float u = 0.0f;
        #pragma unroll
        for (int j = 0; j < 4; ++j) {
            const float xm = ((c0 + j) <= d) ? xv[j] : -1e9f;  // mask -> sp=0
            const float t  = __expf(xm);                       // e^x (v_exp)
            u = fmaf(__log2f(1.0f + t), wl[j], u);
        }
        acc = fmaf(u, sw_i[i], acc);

        // Event term: only the lane owning quad d>>2 contributes -ec * x_d.
        const float xa = (d & 1) ? xv[1] : xv[0];
        const float xb = (d & 1) ? xv[3] : xv[2];
        const float xs = (d & 2) ? xb : xa;
        const bool own = (d >= 0) && ((d >> 2) == q);
        acc = fmaf(own ? -ec_i[i] : 0.0f, xs, acc);
    }

    // ---- Wave butterfly reduction. ----
    #pragma unroll
    for (int off = 32; off >= 1; off >>= 1) {
        acc    += __shfl_xor(acc,    off, 64);
        acc_sw += __shfl_xor(acc_sw, off, 64);
    }

    // ---- Block LDS reduce -> one plain store per block (NO atomics, NO
    // fences: device-scope release ~50 ns/block serialized, Rounds 5/7). ----
    __shared__ float s_loss[4];
    __shared__ float s_sw[4];
    if (lane == 0) {
        s_loss[waveInBlk] = acc;
        s_sw[waveInBlk]   = acc_sw;
    }
    __syncthreads();
    if (threadIdx.x == 0) {
        float bl = 0.f, bs = 0.f;
        #pragma unroll
        for (int w = 0; w < 4; ++w) { bl += s_loss[w]; bs += s_sw[w]; }
        partial_loss[blockIdx.x] = bl;
        partial_sw[blockIdx.x]   = bs;
    }
}

// Single block (512 threads) sums nblocks<=2048 partial pairs via float4.
__global__ __launch_bounds__(512) void nll_hazard_reduce(
    const float* __restrict__ partial_loss,
    const float* __restrict__ partial_sw,
    float* __restrict__ out,
    int nblocks)
{
    const int t    = threadIdx.x;
    const int lane = t & 63;
    const int wid  = t >> 6;

    float l = 0.f, s = 0.f;
    const int nvec = nblocks >> 2;   // nblocks multiple of 4 (grid sizing)
    if (t < nvec) {
        const float4 l4 = reinterpret_cast<const float4*>(partial_loss)[t];
        const float4 s4 = reinterpret_cast<const float4*>(partial_sw)[t];
        l = (l4.x + l4.y) + (l4.z + l4.w);
        s = (s4.x + s4.y) + (s4.z + s4.w);
    }

    #pragma unroll
    for (int off = 32; off >= 1; off >>= 1) {
        l += __shfl_xor(l, off, 64);
        s += __shfl_xor(s, off, 64);
    }

    __shared__ float sl[8];
    __shared__ float ss[8];
    if (lane == 0) { sl[wid] = l; ss[wid] = s; }
    __syncthreads();
    if (t == 0) {
        float L = 0.f, S = 0.f;
        #pragma unroll
        for (int w = 0; w < 8; ++w) { L += sl[w]; S += ss[w]; }
        out[0] = L / fmaxf(S, EPSF);
    }
}

extern "C" void kernel_launch(void* const* d_in, const int* in_sizes, int n_in,
                              void* d_out, int out_size, void* d_ws, size_t ws_size,
                              hipStream_t stream) {
    const float* preds         = (const float*)d_in[0];
    const float* weight        = (const float*)d_in[1];
    const float* sample_weight = (const float*)d_in[2];
    const int*   durations     = (const int*)d_in[3];
    const int*   events        = (const int*)d_in[4];
    float* out = (float*)d_out;

    const int N = in_sizes[2];  // sample_weight has N elements

    const int nblocks = (N + ROWS_PER_BLOCK - 1) / ROWS_PER_BLOCK;  // 2048

    float* partial_loss = (float*)d_ws;             // [nblocks]
    float* partial_sw   = partial_loss + nblocks;   // [nblocks]

    nll_hazard_main<<<nblocks, 256, 0, stream>>>(
        preds, weight, sample_weight, durations, events,
        partial_loss, partial_sw, N);

    nll_hazard_reduce<<<1, 512, 0, stream>>>(partial_loss, partial_sw, out, nblocks);
}